// Round 13
// baseline (231.840 us; speedup 1.0000x reference)
//
#include <hip/hip_runtime.h>

typedef float f32x4 __attribute__((ext_vector_type(4)));
typedef _Float16 f16x8 __attribute__((ext_vector_type(8)));
typedef _Float16 v2h __attribute__((ext_vector_type(2)));
typedef short s16x2 __attribute__((ext_vector_type(2)));

#define NB 128  // partition blocks; ghist layout [bkt*NB + blk]

union h16bits { _Float16 h; unsigned short u; };

__device__ __forceinline__ float hdot2(v2h a, v2h b, float c) {
#if __has_builtin(__builtin_amdgcn_fdot2)
  return __builtin_amdgcn_fdot2(a, b, c, false);
#else
  return c + (float)a[0] * (float)b[0] + (float)a[1] * (float)b[1];
#endif
}

__device__ __forceinline__ v2h relu2(v2h a) {
#if __has_builtin(__builtin_elementwise_max)
  const v2h z = {(_Float16)0, (_Float16)0};
  return __builtin_elementwise_max(a, z);
#else
  const v2h z = {(_Float16)0, (_Float16)0};
  s16x2 m = a > z;
  s16x2 bits = *(s16x2*)&a;
  s16x2 r = bits & m;
  return *(v2h*)&r;
#endif
}

// ---------------------------------------------------------------------------
// Unified prep GEMM (3 roles): writes separate fp16 arrays (ld 128):
//  role 0: Hlo = fp16(hidden), Hws = hidden@Ws
//  role 1: Rlo = fp16(rela),   Rwr = rela@Wr
//  role 2: Rwqr = rela@Wqr + b
// ---------------------------------------------------------------------------
__global__ __launch_bounds__(256) void prep_gemm(
    const float* __restrict__ hidden, const float* __restrict__ rela,
    const float* __restrict__ Ws, const float* __restrict__ Wr,
    const float* __restrict__ Wqr, const float* __restrict__ Wqr_b,
    _Float16* __restrict__ Hlo, _Float16* __restrict__ Hws,
    _Float16* __restrict__ Rlo, _Float16* __restrict__ Rwr,
    _Float16* __restrict__ Rwqr, int n_node, int n_rel,
    int hid_blocks, int rel_blocks) {
  __shared__ _Float16 sW[16384];
  const int bidx = blockIdx.x;
  const float* A;
  const float* W;
  const float* bias = nullptr;
  _Float16* Lo = nullptr;
  _Float16* C;
  int M, bb;
  if (bidx < hid_blocks) {
    bb = bidx; A = hidden; W = Ws; Lo = Hlo; C = Hws; M = n_node;
  } else if (bidx < hid_blocks + rel_blocks) {
    bb = bidx - hid_blocks; A = rela; W = Wr; Lo = Rlo; C = Rwr; M = n_rel;
  } else {
    bb = bidx - hid_blocks - rel_blocks; A = rela; W = Wqr; C = Rwqr;
    bias = Wqr_b; M = n_rel;
  }

  for (int i = threadIdx.x; i < 16384; i += 256) {
    const int k = i >> 7, c = i & 127;
    sW[(k >> 3) * 1024 + c * 8 + (k & 7)] = (_Float16)W[i];
  }
  __syncthreads();

  const int wv = threadIdx.x >> 6, l = threadIdx.x & 63;
  const int row = bb * 64 + wv * 16 + (l & 15);
  const int kb = (l >> 4) * 8;
  const bool rvalid = row < M;

  f16x8 a[4];
#pragma unroll
  for (int kk = 0; kk < 4; ++kk) {
    f16x8 t = {0, 0, 0, 0, 0, 0, 0, 0};
    if (rvalid) {
      const f32x4 lo = *(const f32x4*)(A + (size_t)row * 128 + kb + 32 * kk);
      const f32x4 hi = *(const f32x4*)(A + (size_t)row * 128 + kb + 32 * kk + 4);
      t[0] = (_Float16)lo[0]; t[1] = (_Float16)lo[1];
      t[2] = (_Float16)lo[2]; t[3] = (_Float16)lo[3];
      t[4] = (_Float16)hi[0]; t[5] = (_Float16)hi[1];
      t[6] = (_Float16)hi[2]; t[7] = (_Float16)hi[3];
      if (Lo) *(f16x8*)(Lo + (size_t)row * 128 + kb + 32 * kk) = t;
    }
    a[kk] = t;
  }

  f32x4 acc[8];
#pragma unroll
  for (int n = 0; n < 8; ++n) acc[n] = (f32x4){0.f, 0.f, 0.f, 0.f};
#pragma unroll
  for (int n = 0; n < 8; ++n)
#pragma unroll
    for (int kk = 0; kk < 4; ++kk) {
      const int kg = 4 * kk + (l >> 4);
      const f16x8 bfrag = *(const f16x8*)(sW + kg * 1024 + (16 * n + (l & 15)) * 8);
      acc[n] = __builtin_amdgcn_mfma_f32_16x16x32_f16(a[kk], bfrag, acc[n], 0, 0, 0);
    }

  const int orow_base = bb * 64 + wv * 16 + (l >> 4) * 4;
#pragma unroll
  for (int n = 0; n < 8; ++n) {
    const int col = 16 * n + (l & 15);
    const float badd = bias ? bias[col] : 0.0f;
#pragma unroll
    for (int r4 = 0; r4 < 4; ++r4) {
      const int orow = orow_base + r4;
      if (orow < M)
        C[(size_t)orow * 128 + col] = (_Float16)(acc[n][r4] + badd);
    }
  }
}

// ---------------------------------------------------------------------------
// Fused dispatch: blocks [0,NB) = bucket histogram (as R12 part_hist);
// blocks [NB, ...) = per-edge alpha: ar[e] = (rel<<16) | fp16bits(alpha).
// alpha = sigmoid(wa . relu(Hws[s]+Rwr[r]+Rwqr[qr]) + b). 4 edges x 16 lanes.
// ---------------------------------------------------------------------------
__global__ __launch_bounds__(256) void hist_alpha(
    const int* __restrict__ eobj, const int* __restrict__ esub,
    const int* __restrict__ erel, const int* __restrict__ ridx,
    const int* __restrict__ qrel, const _Float16* __restrict__ Hws,
    const _Float16* __restrict__ Rwr, const _Float16* __restrict__ Rwqr,
    const float* __restrict__ wa_w, const float* __restrict__ wa_b_p,
    int* __restrict__ ghist, int* __restrict__ ar,
    int E, int nbkt, int chunk) {
  __shared__ int lh[128];
  const int bidx = blockIdx.x, t = threadIdx.x;

  if (bidx < NB) {  // histogram role
    for (int i = t; i < nbkt; i += 256) lh[i] = 0;
    __syncthreads();
    const int lo = bidx * chunk, hi = min(lo + chunk, E);
    for (int i = lo + t; i < hi; i += 256) atomicAdd(&lh[eobj[i] >> 9], 1);
    __syncthreads();
    for (int i = t; i < nbkt; i += 256) ghist[i * NB + bidx] = lh[i];
    return;
  }

  // alpha role
  const int wv = t >> 6, l = t & 63;
  const int g = l >> 4;
  const int d0 = (l & 15) * 8;
  const int aw = (bidx - NB) * 4 + wv;
  const int nwaves = (gridDim.x - NB) * 4;

  v2h wa2[4];
  {
    const float4 w0 = *(const float4*)(wa_w + d0);
    const float4 w1 = *(const float4*)(wa_w + d0 + 4);
    wa2[0] = (v2h){(_Float16)w0.x, (_Float16)w0.y};
    wa2[1] = (v2h){(_Float16)w0.z, (_Float16)w0.w};
    wa2[2] = (v2h){(_Float16)w1.x, (_Float16)w1.y};
    wa2[3] = (v2h){(_Float16)w1.z, (_Float16)w1.w};
  }
  const float wab = wa_b_p[0];

  for (int base = aw * 64; base < E; base += nwaves * 64) {
    const int cnt = min(E - base, 64);
    int s = 0, r = 0, q = 0;
    if (l < cnt) {
      const int i = base + l;
      s = esub[i];
      r = erel[i];
      q = qrel[ridx[i]];
    }
    for (int c = 0; c < cnt; c += 4) {
      const int src = c + g;
      const bool valid = src < cnt;
      const int sv = __shfl(s, src);
      const int rv = __shfl(r, src);
      const int qv = __shfl(q, src);

      const f32x4 rw = *(const f32x4*)(Hws + ((size_t)sv << 7) + d0);
      const f32x4 rr = *(const f32x4*)(Rwr + ((size_t)rv << 7) + d0);
      const f32x4 rq = *(const f32x4*)(Rwqr + ((size_t)qv << 7) + d0);
      const v2h* hw = (const v2h*)&rw;
      const v2h* hr_ = (const v2h*)&rr;
      const v2h* hq = (const v2h*)&rq;

      float part = 0.0f;
#pragma unroll
      for (int i = 0; i < 4; ++i)
        part = hdot2(relu2(hw[i] + hr_[i] + hq[i]), wa2[i], part);
      part += __shfl_xor(part, 1);
      part += __shfl_xor(part, 2);
      part += __shfl_xor(part, 4);
      part += __shfl_xor(part, 8);

      if (valid && (l & 15) == 0) {
        const float alpha = 1.0f / (1.0f + __expf(-(part + wab)));
        h16bits hb;
        hb.h = (_Float16)alpha;
        ar[base + src] = (rv << 16) | hb.u;
      }
    }
  }
}

// ---------------------------------------------------------------------------
// Deterministic partition, zero global atomics (R12). Payload now
// (sub, e<<9 | lobj) — alpha/rel picked up later from ar[e].
// ---------------------------------------------------------------------------
__global__ __launch_bounds__(256) void part_scatter(
    const int* __restrict__ eobj, const int* __restrict__ esub,
    const int* __restrict__ ghist, int* __restrict__ bstart,
    int* __restrict__ offs, int2* __restrict__ tmp,
    int E, int n, int nbkt, int chunk) {
  __shared__ int s[128];
  __shared__ int scur[128];
  const int b = blockIdx.x, t = threadIdx.x;

  int pre = 0, tot = 0;
  if (t < nbkt) {
#pragma unroll 8
    for (int k = 0; k < NB; ++k) {
      const int v = ghist[t * NB + k];
      pre += (k < b) ? v : 0;
      tot += v;
    }
  }
  if (t < 128) s[t] = (t < nbkt) ? tot : 0;
  __syncthreads();
  if (t < 128) {
    for (int o = 1; o < 128; o <<= 1) {
      const int a = (t >= o) ? s[t - o] : 0;
      __syncthreads();
      s[t] += a;
      __syncthreads();
    }
  } else {
    for (int o = 1; o < 128; o <<= 1) { __syncthreads(); __syncthreads(); }
  }
  if (t < nbkt) {
    const int bucket_start = s[t] - tot;
    scur[t] = bucket_start + pre;
    if (b == 0) bstart[t] = bucket_start;
  }
  if (b == 0 && t == 0) { bstart[nbkt] = E; offs[n] = E; }
  __syncthreads();

  const int lo = b * chunk, hi = min(lo + chunk, E);
  for (int i = lo + t; i < hi; i += 256) {
    const int obj = eobj[i];
    const int bkt = obj >> 9;
    const int p = atomicAdd(&scur[bkt], 1);
    tmp[p] = make_int2(esub[i], (i << 9) | (obj & 511));
  }
}

// ---------------------------------------------------------------------------
// One block per bucket: per-node count -> scan -> offs -> LDS scatter ->
// coalesced CSR write of (sub, rel<<16|alpha16) (folds in ar[e]).
// ---------------------------------------------------------------------------
__global__ __launch_bounds__(256) void bucket_sort(
    const int2* __restrict__ tmp, const int* __restrict__ ar,
    const int* __restrict__ bstart, int* __restrict__ offs,
    int2* __restrict__ ssrq, int n) {
  __shared__ int2 stage[8192];
  __shared__ int scnt[512];
  __shared__ int scur[512];
  const int b = blockIdx.x, t = threadIdx.x;
  const int s0 = bstart[b], s1 = bstart[b + 1];
  const int cnt = s1 - s0;
  const int node0 = b * 512;

  scnt[t] = 0;
  scnt[t + 256] = 0;
  __syncthreads();
  for (int i = t; i < cnt; i += 256) atomicAdd(&scnt[tmp[s0 + i].y & 511], 1);
  __syncthreads();

  const int d0 = scnt[t], d1 = scnt[t + 256];
  __syncthreads();
  for (int o = 1; o < 512; o <<= 1) {
    const int a0 = (t >= o) ? scnt[t - o] : 0;
    const int a1 = (t + 256 >= o) ? scnt[t + 256 - o] : 0;
    __syncthreads();
    scnt[t] += a0;
    scnt[t + 256] += a1;
    __syncthreads();
  }
  const int e0 = scnt[t] - d0, e1 = scnt[t + 256] - d1;
  scur[t] = e0;
  scur[t + 256] = e1;
  if (node0 + t < n) offs[node0 + t] = s0 + e0;
  if (node0 + t + 256 < n) offs[node0 + t + 256] = s0 + e1;
  __syncthreads();

  if (cnt <= 8192) {
    for (int i = t; i < cnt; i += 256) {
      const int2 p = tmp[s0 + i];
      const int q = atomicAdd(&scur[p.y & 511], 1);
      stage[q] = make_int2(p.x, ar[p.y >> 9]);
    }
    __syncthreads();
    for (int i = t; i < cnt; i += 256) ssrq[s0 + i] = stage[i];
  } else {
    for (int i = t; i < cnt; i += 256) {
      const int2 p = tmp[s0 + i];
      const int q = atomicAdd(&scur[p.y & 511], 1);
      ssrq[s0 + q] = make_int2(p.x, ar[p.y >> 9]);
    }
  }
}

// ---------------------------------------------------------------------------
// Lite per-node reduce: acc += alpha * Hlo[s] * Rlo[r]. No shfl-reduce, no
// expf — pure gather + packed FMA. One wave/node, 4 edges x 16 lanes.
// ---------------------------------------------------------------------------
__global__ __launch_bounds__(256) void reduce_lite(
    const int2* __restrict__ ssrq, const int* __restrict__ offs,
    const _Float16* __restrict__ Hlo, const _Float16* __restrict__ Rlo,
    _Float16* __restrict__ agg, int n_node) {
  const int node = (blockIdx.x * blockDim.x + threadIdx.x) >> 6;
  if (node >= n_node) return;
  const int l = threadIdx.x & 63;
  const int g = l >> 4;
  const int d0 = (l & 15) * 8;

  const int start = offs[node], end = offs[node + 1];
  v2h acc2[4] = {};

  for (int base = start; base < end; base += 64) {
    const int cnt = min(end - base, 64);
    int s_all = 0, ra_all = 0;
    if (l < cnt) { const int2 sr = ssrq[base + l]; s_all = sr.x; ra_all = sr.y; }
    for (int c = 0; c < cnt; c += 4) {
      const int src = c + g;
      const bool valid = src < cnt;
      const int sv = __shfl(s_all, src);
      const int rav = __shfl(ra_all, src);
      const int rv = rav >> 16;

      h16bits hb;
      hb.u = (unsigned short)(rav & 0xffff);
      const _Float16 ah = valid ? hb.h : (_Float16)0;
      const v2h alpha2 = {ah, ah};

      const f32x4 rh = *(const f32x4*)(Hlo + ((size_t)sv << 7) + d0);
      const f32x4 rg = *(const f32x4*)(Rlo + ((size_t)rv << 7) + d0);
      const v2h* hh = (const v2h*)&rh;
      const v2h* hg = (const v2h*)&rg;
#pragma unroll
      for (int i = 0; i < 4; ++i) acc2[i] += alpha2 * (hh[i] * hg[i]);
    }
  }

#pragma unroll
  for (int i = 0; i < 4; ++i) {
    unsigned x = *(unsigned*)&acc2[i];
    unsigned y = (unsigned)__shfl_xor((int)x, 16);
    acc2[i] += *(v2h*)&y;
    x = *(unsigned*)&acc2[i];
    y = (unsigned)__shfl_xor((int)x, 32);
    acc2[i] += *(v2h*)&y;
  }
  if (l < 16)
    *(f32x4*)(agg + (size_t)node * 128 + d0) = *(f32x4*)acc2;
}

// ---------------------------------------------------------------------------
// Final projection: out f32 = agg fp16 @ Wh (Wh staged f32->fp16 LDS).
// ---------------------------------------------------------------------------
__global__ __launch_bounds__(256) void gemm_final(
    const _Float16* __restrict__ agg, const float* __restrict__ Wh,
    float* __restrict__ out, int M) {
  __shared__ _Float16 sW[16384];
  for (int i = threadIdx.x; i < 16384; i += 256) {
    const int k = i >> 7, c = i & 127;
    sW[(k >> 3) * 1024 + c * 8 + (k & 7)] = (_Float16)Wh[i];
  }
  __syncthreads();

  const int wv = threadIdx.x >> 6, l = threadIdx.x & 63;
  const int row = blockIdx.x * 64 + wv * 16 + (l & 15);
  const int kb = (l >> 4) * 8;
  const bool rvalid = row < M;

  f16x8 a[4];
#pragma unroll
  for (int kk = 0; kk < 4; ++kk) {
    f16x8 t = {0, 0, 0, 0, 0, 0, 0, 0};
    if (rvalid) t = *(const f16x8*)(agg + (size_t)row * 128 + kb + 32 * kk);
    a[kk] = t;
  }

  f32x4 acc[8];
#pragma unroll
  for (int n = 0; n < 8; ++n) acc[n] = (f32x4){0.f, 0.f, 0.f, 0.f};
#pragma unroll
  for (int n = 0; n < 8; ++n)
#pragma unroll
    for (int kk = 0; kk < 4; ++kk) {
      const int kg = 4 * kk + (l >> 4);
      const f16x8 bfrag = *(const f16x8*)(sW + kg * 1024 + (16 * n + (l & 15)) * 8);
      acc[n] = __builtin_amdgcn_mfma_f32_16x16x32_f16(a[kk], bfrag, acc[n], 0, 0, 0);
    }

  const int orow_base = blockIdx.x * 64 + wv * 16 + (l >> 4) * 4;
#pragma unroll
  for (int n = 0; n < 8; ++n) {
    const int col = 16 * n + (l & 15);
#pragma unroll
    for (int r4 = 0; r4 < 4; ++r4) {
      const int orow = orow_base + r4;
      if (orow < M) out[(size_t)orow * 128 + col] = acc[n][r4];
    }
  }
}

// ---------------------------------------------------------------------------
extern "C" void kernel_launch(void* const* d_in, const int* in_sizes, int n_in,
                              void* d_out, int out_size, void* d_ws, size_t ws_size,
                              hipStream_t stream) {
  const int* q_rel = (const int*)d_in[1];
  const int* r_idx = (const int*)d_in[2];
  const float* hidden = (const float*)d_in[3];
  const int* edge_sub = (const int*)d_in[4];
  const int* edge_rel = (const int*)d_in[5];
  const int* edge_obj = (const int*)d_in[6];
  const float* rela = (const float*)d_in[8];
  const float* Ws = (const float*)d_in[9];
  const float* Wr = (const float*)d_in[10];
  const float* Wqr_w = (const float*)d_in[11];
  const float* Wqr_b = (const float*)d_in[12];
  const float* wa_w = (const float*)d_in[13];
  const float* wa_b = (const float*)d_in[14];
  const float* Wh = (const float*)d_in[15];

  const int E = in_sizes[2];
  const int n_node = in_sizes[3] / 128;
  const int n_rel = in_sizes[8] / 128;
  float* out = (float*)d_out;

  const int nbkt = (n_node + 511) / 512;  // 98
  const int chunk = (E + NB - 1) / NB;

  auto al = [](size_t x) { return (x + 511) & ~(size_t)511; };
  char* ws = (char*)d_ws;
  size_t o = 0;
  _Float16* Hlo = (_Float16*)(ws + o);   o += al((size_t)n_node * 128 * 2);
  _Float16* Hws = (_Float16*)(ws + o);   o += al((size_t)n_node * 128 * 2);
  _Float16* agg = (_Float16*)(ws + o);   o += al((size_t)n_node * 128 * 2);
  _Float16* Rlo = (_Float16*)(ws + o);   o += al((size_t)n_rel * 128 * 2);
  _Float16* Rwr = (_Float16*)(ws + o);   o += al((size_t)n_rel * 128 * 2);
  _Float16* Rwqr = (_Float16*)(ws + o);  o += al((size_t)n_rel * 128 * 2);
  int* offs = (int*)(ws + o);      o += al((size_t)(n_node + 1) * 4);
  int* ghist = (int*)(ws + o);     o += al((size_t)nbkt * NB * 4);
  int* bstart = (int*)(ws + o);    o += al((size_t)(nbkt + 1) * 4);
  int* ar = (int*)(ws + o);        o += al((size_t)E * 4);
  int2* tmp = (int2*)(ws + o);     o += al((size_t)E * 8);
  int2* ssrq = (int2*)(ws + o);    o += al((size_t)E * 8);

  const int hid_blocks = (n_node + 63) / 64;
  const int rel_blocks = (n_rel + 63) / 64;

  // 1: projections (Hlo/Hws/Rlo/Rwr/Rwqr)
  prep_gemm<<<dim3(hid_blocks + 2 * rel_blocks), dim3(256), 0, stream>>>(
      hidden, rela, Ws, Wr, Wqr_w, Wqr_b, Hlo, Hws, Rlo, Rwr, Rwqr,
      n_node, n_rel, hid_blocks, rel_blocks);

  // 2: bucket histogram || per-edge alpha
  hist_alpha<<<dim3(NB + 2048), dim3(256), 0, stream>>>(
      edge_obj, edge_sub, edge_rel, r_idx, q_rel, Hws, Rwr, Rwqr,
      wa_w, wa_b, ghist, ar, E, nbkt, chunk);

  // 3: deterministic partition (no global atomics)
  part_scatter<<<dim3(NB), dim3(256), 0, stream>>>(
      edge_obj, edge_sub, ghist, bstart, offs, tmp, E, n_node, nbkt, chunk);

  // 4: per-bucket LDS sort + alpha fold-in
  bucket_sort<<<dim3(nbkt), dim3(256), 0, stream>>>(tmp, ar, bstart, offs,
                                                    ssrq, n_node);

  // 5: lite gather-FMA reduce
  const int rblocks = (n_node * 64 + 255) / 256;
  reduce_lite<<<dim3(rblocks), dim3(256), 0, stream>>>(
      ssrq, offs, Hlo, Rlo, agg, n_node);

  // 6: final projection
  gemm_final<<<dim3(hid_blocks), dim3(256), 0, stream>>>(agg, Wh, out, n_node);
}